// Round 1
// baseline (945.063 us; speedup 1.0000x reference)
//
#include <hip/hip_runtime.h>
#include <stdint.h>
#include <stddef.h>

// Problem constants (fixed by reference: B=8, T=4000)
#define NTOK   32000      // B*T
#define HID    1024
#define NQKV   3072
#define CTX    200
#define NH     16

typedef _Float16 f16;
typedef _Float16 f16x8 __attribute__((ext_vector_type(8)));
typedef _Float16 f16x4 __attribute__((ext_vector_type(4)));
typedef float    f32x4 __attribute__((ext_vector_type(4)));

__device__ __forceinline__ void async_copy16(const void* g, void* l) {
  typedef const __attribute__((address_space(1))) char gchar;
  typedef __attribute__((address_space(3))) char lchar;
  __builtin_amdgcn_global_load_lds((gchar*)g, (lchar*)l, 16, 0, 0);
}

// ---------------------------------------------------------------------------
// prep: wt_qkv[n][k] = [wq|wkv]^T as f16 ; wt_o[n][k] = wo^T ; rel -> f16
// ---------------------------------------------------------------------------
__global__ __launch_bounds__(256) void prep_kernel(
    const float* __restrict__ wq, const float* __restrict__ wkv,
    const float* __restrict__ wo, const float* __restrict__ rel,
    f16* __restrict__ wt_qkv, f16* __restrict__ wt_o, f16* __restrict__ rel_h) {
  long idx = (long)blockIdx.x * 256 + threadIdx.x;
  if (idx < (long)NQKV * HID) {
    int n = (int)(idx >> 10), k = (int)(idx & 1023);
    float v = (n < 1024) ? wq[(size_t)k * 1024 + n] : wkv[(size_t)k * 2048 + (n - 1024)];
    wt_qkv[idx] = (f16)v;
    return;
  }
  idx -= (long)NQKV * HID;
  if (idx < (long)HID * HID) {
    int n = (int)(idx >> 10), k = (int)(idx & 1023);
    wt_o[idx] = (f16)wo[(size_t)k * 1024 + n];
    return;
  }
  idx -= (long)HID * HID;
  if (idx < 1025 * 64) rel_h[idx] = (f16)rel[idx];
}

// ---------------------------------------------------------------------------
// LayerNorm: one block per token, 256 threads * float4, fp32 reduce -> f16 x
// ---------------------------------------------------------------------------
__global__ __launch_bounds__(256) void ln_kernel(
    const float* __restrict__ hs, const float* __restrict__ lw,
    const float* __restrict__ lb, f16* __restrict__ x) {
  int tok = blockIdx.x;
  int t = threadIdx.x;
  const float4* src = (const float4*)(hs + (size_t)tok * HID);
  float4 v = src[t];
  float s  = v.x + v.y + v.z + v.w;
  float s2 = v.x * v.x + v.y * v.y + v.z * v.z + v.w * v.w;
  for (int m = 1; m < 64; m <<= 1) { s += __shfl_xor(s, m); s2 += __shfl_xor(s2, m); }
  __shared__ float ps[4], ps2[4];
  int w = t >> 6;
  if ((t & 63) == 0) { ps[w] = s; ps2[w] = s2; }
  __syncthreads();
  s  = ps[0] + ps[1] + ps[2] + ps[3];
  s2 = ps2[0] + ps2[1] + ps2[2] + ps2[3];
  float mu  = s * (1.0f / 1024.0f);
  float var = s2 * (1.0f / 1024.0f) - mu * mu;
  float rs  = rsqrtf(var + 1e-5f);
  float4 wv = ((const float4*)lw)[t];
  float4 bv = ((const float4*)lb)[t];
  f16x4 o;
  o[0] = (f16)((v.x - mu) * rs * wv.x + bv.x);
  o[1] = (f16)((v.y - mu) * rs * wv.y + bv.y);
  o[2] = (f16)((v.z - mu) * rs * wv.z + bv.z);
  o[3] = (f16)((v.w - mu) * rs * wv.w + bv.w);
  *(f16x4*)(x + (size_t)tok * HID + t * 4) = o;
}

// ---------------------------------------------------------------------------
// GEMM: C[M,N] = A[M,1024] @ Bt[N,1024]^T, fp16 in / fp32 acc.
// 128x128 tile, BK=32, global_load_lds(16B), XOR-swizzled LDS.
// Swizzle: logical k-granule kg (8 halves) of row r stored at phys granule
// kg ^ ((r>>1)&3)  -> ds_read_b128 fragment loads are ~2-way (free).
// EPI==0: store f16. EPI==1: store f32 + bias.
// ---------------------------------------------------------------------------
template <int EPI>
__global__ __launch_bounds__(256) void gemm_kernel(
    const f16* __restrict__ A, const f16* __restrict__ Bt,
    void* __restrict__ C, const float* __restrict__ bias, int N) {
  __shared__ __attribute__((aligned(16))) f16 As[128 * 32];
  __shared__ __attribute__((aligned(16))) f16 Bs[128 * 32];
  int t = threadIdx.x;
  int w = t >> 6, l = t & 63;
  int m0 = blockIdx.y * 128;
  int n0 = blockIdx.x * 128;
  int wm = w >> 1, wn = w & 1;
  f32x4 acc[4][4] = {};
  int sr = t >> 2;   // staging row within 64-row half-tile
  int pg = t & 3;    // physical granule
  int lr = l & 15, lk = l >> 4;

  for (int k0 = 0; k0 < 1024; k0 += 32) {
    __syncthreads();
    #pragma unroll
    for (int c = 0; c < 2; ++c) {
      int r  = c * 64 + sr;
      int kg = pg ^ ((r >> 1) & 3);
      async_copy16(A  + (size_t)(m0 + r) * 1024 + k0 + kg * 8, (char*)As + c * 4096 + w * 1024);
      async_copy16(Bt + (size_t)(n0 + r) * 1024 + k0 + kg * 8, (char*)Bs + c * 4096 + w * 1024);
    }
    __syncthreads();
    f16x8 af[4], bf[4];
    #pragma unroll
    for (int mt = 0; mt < 4; ++mt) {
      int row = wm * 64 + mt * 16 + lr;
      int g = lk ^ ((row >> 1) & 3);
      af[mt] = *(const f16x8*)((const char*)As + row * 64 + g * 16);
    }
    #pragma unroll
    for (int nt = 0; nt < 4; ++nt) {
      int row = wn * 64 + nt * 16 + lr;
      int g = lk ^ ((row >> 1) & 3);
      bf[nt] = *(const f16x8*)((const char*)Bs + row * 64 + g * 16);
    }
    #pragma unroll
    for (int mt = 0; mt < 4; ++mt)
      #pragma unroll
      for (int nt = 0; nt < 4; ++nt)
        acc[mt][nt] = __builtin_amdgcn_mfma_f32_16x16x32_f16(af[mt], bf[nt], acc[mt][nt], 0, 0, 0);
  }

  #pragma unroll
  for (int mt = 0; mt < 4; ++mt)
    #pragma unroll
    for (int nt = 0; nt < 4; ++nt) {
      int gcol = n0 + wn * 64 + nt * 16 + lr;
      #pragma unroll
      for (int r = 0; r < 4; ++r) {
        int grow = m0 + wm * 64 + mt * 16 + lk * 4 + r;
        float v = acc[mt][nt][r];
        if constexpr (EPI == 0) {
          ((f16*)C)[(size_t)grow * N + gcol] = (f16)v;
        } else {
          ((float*)C)[(size_t)grow * N + gcol] = v + bias[gcol];
        }
      }
    }
}

// ---------------------------------------------------------------------------
// Block attention, one workgroup (4 waves) per (b, n, h) block-head.
// Scores S[i,j] = q_i . k_j  + q_i . rel_emb[i-j+512]  (both via one kind of
// MFMA pass: K rows from LDS, rel rows read straight from global (L2-hot));
// rel contributions scatter-add into S at j = i - p + 199 (unique targets).
// Softmax fp32, PV via P @ Vt MFMA. 16-row chunks, 3 barriers per chunk.
// ---------------------------------------------------------------------------
__global__ __launch_bounds__(256) void attn_kernel(
    const f16* __restrict__ qkv, const f16* __restrict__ rel_h,
    f16* __restrict__ out) {
  __shared__ __attribute__((aligned(16))) f16  Kp[208 * 72];    // keys, padded
  __shared__ __attribute__((aligned(16))) f16  Vt[64 * 232];    // V transposed [d][j]
  __shared__ __attribute__((aligned(16))) float Sqk[16 * 212];  // scores chunk
  __shared__ __attribute__((aligned(16))) f16  P[16 * 232];     // probs chunk

  int bh = blockIdx.x;
  int h  = bh & 15;
  int bn = bh >> 4;
  size_t t0 = (size_t)bn * CTX;
  int t = threadIdx.x;
  int w = t >> 6, l = t & 63;
  int lr = l & 15, lk = l >> 4;
  const float scale = 0.125f;

  // ---- stage K (200 rows) + zero pad rows 200..207
  const f16* kbase = qkv + t0 * NQKV + 1024 + h * 64;
  for (int idx = t; idx < 200 * 8; idx += 256) {
    int row = idx >> 3, g = idx & 7;
    *(float4*)(Kp + row * 72 + g * 8) = *(const float4*)(kbase + (size_t)row * NQKV + g * 8);
  }
  if (t < 64) {
    float4 z = {0.f, 0.f, 0.f, 0.f};
    int row = 200 + (t >> 3), g = t & 7;
    *(float4*)(Kp + row * 72 + g * 8) = z;
  }
  // ---- stage V transposed, zero cols 200..223
  const f16* vbase = qkv + t0 * NQKV + 2048 + h * 64;
  for (int idx = t; idx < 200 * 64; idx += 256) {
    int j = idx >> 6, d = idx & 63;
    Vt[d * 232 + j] = vbase[(size_t)j * NQKV + d];
  }
  for (int idx = t; idx < 64 * 24; idx += 256) {
    int d = idx / 24, j = 200 + idx % 24;
    Vt[d * 232 + j] = (f16)0.f;
  }
  __syncthreads();

  const f16* qbase = qkv + t0 * NQKV + h * 64;

  for (int m0 = 0; m0 < 200; m0 += 16) {
    // A fragments (Q rows) straight from global (L1/L2 hot)
    int qrow = m0 + lr; if (qrow > 199) qrow = 199;
    f16x8 aq0 = *(const f16x8*)(qbase + (size_t)qrow * NQKV + lk * 8);
    f16x8 aq1 = *(const f16x8*)(qbase + (size_t)qrow * NQKV + 32 + lk * 8);

    // ---- QK: n-tiles 0..12 (keys from LDS)
    for (int nt = w; nt < 13; nt += 4) {
      f32x4 acc = {};
      f16x8 b0 = *(const f16x8*)(Kp + (nt * 16 + lr) * 72 + lk * 8);
      f16x8 b1 = *(const f16x8*)(Kp + (nt * 16 + lr) * 72 + 32 + lk * 8);
      acc = __builtin_amdgcn_mfma_f32_16x16x32_f16(aq0, b0, acc, 0, 0, 0);
      acc = __builtin_amdgcn_mfma_f32_16x16x32_f16(aq1, b1, acc, 0, 0, 0);
      #pragma unroll
      for (int r = 0; r < 4; ++r) {
        int i = lk * 4 + r;
        Sqk[i * 212 + nt * 16 + lr] = acc[r];
      }
    }
    __syncthreads();
    // ---- rel-pos: n-tiles 13..37, B rows from global rel table, scatter-add
    for (int nt = 13 + w; nt < 38; nt += 4) {
      f32x4 acc = {};
      int c = nt * 16 + lr;          // 208..607
      int p = c - 208;               // 0..399
      const f16* rb = rel_h + (size_t)(313 + p) * 64;
      f16x8 b0 = *(const f16x8*)(rb + lk * 8);
      f16x8 b1 = *(const f16x8*)(rb + 32 + lk * 8);
      acc = __builtin_amdgcn_mfma_f32_16x16x32_f16(aq0, b0, acc, 0, 0, 0);
      acc = __builtin_amdgcn_mfma_f32_16x16x32_f16(aq1, b1, acc, 0, 0, 0);
      #pragma unroll
      for (int r = 0; r < 4; ++r) {
        int i = lk * 4 + r;
        int j = m0 + i - c + 407;    // j = i_global - p + 199, unique targets
        if (j >= 0 && j < 200) Sqk[i * 212 + j] += acc[r];
      }
    }
    __syncthreads();
    // ---- softmax: 16 threads per row
    {
      int r = t >> 4;
      int g = t & 15;
      float vals[13];
      float mx = -1e30f;
      #pragma unroll
      for (int it = 0; it < 13; ++it) {
        int j = g + 16 * it;
        float v = (j < 200) ? scale * Sqk[r * 212 + j] : -1e30f;
        vals[it] = v;
        mx = fmaxf(mx, v);
      }
      #pragma unroll
      for (int m = 1; m < 16; m <<= 1) mx = fmaxf(mx, __shfl_xor(mx, m));
      float sum = 0.f;
      #pragma unroll
      for (int it = 0; it < 13; ++it) {
        int j = g + 16 * it;
        float e = (j < 200) ? __expf(vals[it] - mx) : 0.f;
        vals[it] = e;
        sum += e;
      }
      #pragma unroll
      for (int m = 1; m < 16; m <<= 1) sum += __shfl_xor(sum, m);
      float inv = 1.0f / sum;
      #pragma unroll
      for (int it = 0; it < 13; ++it) {
        int j = g + 16 * it;
        P[r * 232 + j] = (f16)(vals[it] * inv);
      }
      P[r * 232 + 208 + g] = (f16)0.f;   // zero cols 208..223
    }
    __syncthreads();
    // ---- PV: wave w owns d0 = 16*w
    {
      int d0 = w * 16;
      f32x4 acc = {};
      #pragma unroll
      for (int ks = 0; ks < 7; ++ks) {
        int k0 = ks * 32;
        f16x8 ap = *(const f16x8*)(P + lr * 232 + k0 + lk * 8);
        f16x8 bv = *(const f16x8*)(Vt + (d0 + lr) * 232 + k0 + lk * 8);
        acc = __builtin_amdgcn_mfma_f32_16x16x32_f16(ap, bv, acc, 0, 0, 0);
      }
      #pragma unroll
      for (int r = 0; r < 4; ++r) {
        int i = lk * 4 + r;
        if (m0 + i < 200)
          out[(t0 + m0 + i) * HID + h * 64 + d0 + lr] = (f16)acc[r];
      }
    }
    // no trailing barrier needed: next QK writes Sqk, PV reads only P/Vt,
    // and barrier #1 of next chunk orders everything else.
  }
}

// ---------------------------------------------------------------------------
extern "C" void kernel_launch(void* const* d_in, const int* in_sizes, int n_in,
                              void* d_out, int out_size, void* d_ws, size_t ws_size,
                              hipStream_t stream) {
  const float* hs  = (const float*)d_in[0];
  const float* lnw = (const float*)d_in[1];
  const float* lnb = (const float*)d_in[2];
  const float* wq  = (const float*)d_in[3];
  const float* wkv = (const float*)d_in[4];
  const float* wo  = (const float*)d_in[5];
  const float* bo  = (const float*)d_in[6];
  const float* rel = (const float*)d_in[7];

  // workspace layout (bytes), 256-aligned; total ~258 MB
  char* ws = (char*)d_ws;
  f16* x     = (f16*)(ws);                         // 32000*1024*2 = 65,536,000
  f16* qkv   = (f16*)(ws + 65536000);              // 32000*3072*2 = 196,608,000
  f16* wtqkv = (f16*)(ws + 65536000 + 196608000);                  // 6,291,456
  f16* wto   = (f16*)(ws + 65536000 + 196608000 + 6291456);        // 2,097,152
  f16* rel_h = (f16*)(ws + 65536000 + 196608000 + 6291456 + 2097152); // 131,200
  f16* attn  = x;  // attention output aliases x (x dead after QKV GEMM)

  {
    long total = (long)NQKV * HID + (long)HID * HID + 1025 * 64;
    int grid = (int)((total + 255) / 256);
    prep_kernel<<<grid, 256, 0, stream>>>(wq, wkv, wo, rel, wtqkv, wto, rel_h);
  }
  ln_kernel<<<NTOK, 256, 0, stream>>>(hs, lnw, lnb, x);
  gemm_kernel<0><<<dim3(NQKV / 128, NTOK / 128), 256, 0, stream>>>(x, wtqkv, (void*)qkv, nullptr, NQKV);
  attn_kernel<<<2560, 256, 0, stream>>>(qkv, rel_h, attn);
  gemm_kernel<1><<<dim3(HID / 128, NTOK / 128), 256, 0, stream>>>(attn, wto, d_out, bo, HID);
}